// Round 6
// baseline (2723.770 us; speedup 1.0000x reference)
//
#include <hip/hip_runtime.h>
#include <stdint.h>

#define QN 512
#define DN 1024
#define BN 64
#define LN 1024

typedef _Float16 f16x8 __attribute__((ext_vector_type(8)));
typedef _Float16 f16x4 __attribute__((ext_vector_type(4)));
typedef float f32x4 __attribute__((ext_vector_type(4)));

// async global->LDS DMA, 16B per lane, lane-linear LDS placement
#define DMA16(gp, lp)                                                        \
  __builtin_amdgcn_global_load_lds(                                          \
      (const __attribute__((address_space(1))) uint32_t*)(const void*)(gp),  \
      (__attribute__((address_space(3))) uint32_t*)(void*)(lp), 16, 0, 0)

// ---------------- kernel 1a: tokens fp32 -> staged DMA images
// T2[b][s][off]  : step-s (d-chunk 32) LDS image for k_scores (rows=l, k=d)
// TT2[b][s2][off]: step-s2 (l-chunk 32) LDS image for k_agg   (rows=d, k=l)
// Image layout (64 KB = 64 slabs x 1 KB), for (row R, kk in [0,32)):
//   slab=R>>4, r4=R&15, g=kk>>3, e=kk&7, m=(g+((r4>>1)&3))&3,
//   off = slab*512 + (r4*4+m)*8 + e     (f16 units)
__global__ __launch_bounds__(256) void k_convert(const float* __restrict__ tok,
                                                 _Float16* __restrict__ T2,
                                                 _Float16* __restrict__ TT2) {
  __shared__ __align__(16) _Float16 tile[64][68];
  const int b = blockIdx.z;
  const int l0 = blockIdx.y * 64, d0 = blockIdx.x * 64;
  const int tid = threadIdx.x;
  const int rr = tid >> 4;
  const int cq = tid & 15;
  const int g = (cq >> 1) & 3;     // 16B group within 32-k chunk
  const int e0 = (cq & 1) * 4;     // f16 offset within 16B slot
  const int sq = cq >> 3;          // image index offset
  const size_t base = (size_t)b * LN * DN;
  const size_t ib = (size_t)b * 1048576;  // 1M f16 per b per array
#pragma unroll
  for (int p = 0; p < 4; ++p) {
    const int l = l0 + p * 16 + rr;
    const float4 v = *(const float4*)(tok + base + (size_t)l * DN + d0 + cq * 4);
    f16x4 hv;
    hv[0] = (_Float16)v.x; hv[1] = (_Float16)v.y; hv[2] = (_Float16)v.z; hv[3] = (_Float16)v.w;
    // T2: R=l, d-chunk s
    const int s = (d0 >> 5) + sq;
    const int slab = l >> 4, r4 = l & 15;
    const int m = (g + ((r4 >> 1) & 3)) & 3;
    const int off = slab * 512 + (r4 * 4 + m) * 8 + e0;
    *(f16x4*)(T2 + ib + (size_t)s * 32768 + off) = hv;
    const int ll = p * 16 + rr;
    tile[cq * 4 + 0][ll] = hv[0];
    tile[cq * 4 + 1][ll] = hv[1];
    tile[cq * 4 + 2][ll] = hv[2];
    tile[cq * 4 + 3][ll] = hv[3];
  }
  __syncthreads();
#pragma unroll
  for (int p = 0; p < 4; ++p) {
    const int dl = p * 16 + rr;
    const int d = d0 + dl;
    const f16x4 hv = *(const f16x4*)(&tile[dl][cq * 4]);
    // TT2: R=d, l-chunk s2
    const int s2 = (l0 >> 5) + sq;
    const int slab = d >> 4, r4 = d & 15;
    const int m = (g + ((r4 >> 1) & 3)) & 3;
    const int off = slab * 512 + (r4 * 4 + m) * 8 + e0;
    *(f16x4*)(TT2 + ib + (size_t)s2 * 32768 + off) = hv;
  }
}

// ---------------- kernel 1b: queries fp32 -> f16 + 1/max(||q||,eps)
__global__ __launch_bounds__(256) void k_queries(const float* __restrict__ q,
                                                 _Float16* __restrict__ Qh,
                                                 float* __restrict__ invqn) {
  const int qr = blockIdx.x;
  const int tid = threadIdx.x;
  const float4 v = *(const float4*)(q + (size_t)qr * DN + tid * 4);
  float ss = v.x * v.x + v.y * v.y + v.z * v.z + v.w * v.w;
#pragma unroll
  for (int off = 1; off < 64; off <<= 1) ss += __shfl_xor(ss, off, 64);
  __shared__ float red[4];
  if ((tid & 63) == 0) red[tid >> 6] = ss;
  __syncthreads();
  const float tot = red[0] + red[1] + red[2] + red[3];
  f16x4 hv;
  hv[0] = (_Float16)v.x; hv[1] = (_Float16)v.y; hv[2] = (_Float16)v.z; hv[3] = (_Float16)v.w;
  *(f16x4*)(Qh + (size_t)qr * DN + tid * 4) = hv;
  if (tid == 0) invqn[qr] = 1.0f / fmaxf(sqrtf(tot), 1e-12f);
}

// r10 decode: 256 blocks = 64 b x 4 q-tiles (128 q each); all 4 blocks of a b
// land on the same XCD and (grid == 256 == CU count) run concurrently.
__device__ __forceinline__ void decode_bq(int g, int& b, int& q0) {
  const int xcd = g & 7;
  const int t = g >> 3;          // 0..31
  const int qt4 = t & 3;         // q-tile
  b = ((t >> 2) << 3) | xcd;     // 0..63
  q0 = qt4 * 128;
}

// ---------------- kernel 2: scores + exact softmax + num + P (normalized attn, f16)
// r10: 1024-thread / 16-wave blocks, 128q x 1024l per block; wave owns
// 128q x 64l (4 slabs of the step image) -> B staging stays WAVE-PRIVATE so
// the verified barrier-free counted-vmcnt pipeline (r6/r9) carries unchanged:
// per iter 8 A-loads + 4 B-DMAs = 12 ops -> vmcnt(12). Halves per-GEMM slab
// traffic (256 blocks x 2 MB) and doubles waves/SIMD (2->4).
__global__ __launch_bounds__(1024, 1) void k_scores(const _Float16* __restrict__ Qh,
                                                    const _Float16* __restrict__ T2,
                                                    _Float16* __restrict__ P,
                                                    float* __restrict__ numv) {
  __shared__ __align__(16) _Float16 Bb[2][32768];  // 2 x 64KB step images
  __shared__ float maxbuf[16][128];
  __shared__ float sumbuf[16][128];
  __shared__ float numbuf[16][128];
  __shared__ float Mbuf[128];
  __shared__ float Rbuf[128];
  int b, q0;
  decode_bq(blockIdx.x, b, q0);
  const int tid = threadIdx.x;
  const int w = tid >> 6, lane = tid & 63, c = lane & 15, quad = lane >> 4;

  // contiguous per-lane DMA source into the step image
  const char* __restrict__ gB = (const char*)(T2 + (size_t)b * 1048576) + lane * 16;
  const _Float16* __restrict__ gA = Qh + (size_t)q0 * DN;

  // fragment LDS offsets (f16 units): slab*512 + row*32 + swizzled-colgroup*8
  const int bswz = ((quad + ((c >> 1) & 3)) & 3) * 8;
  const int boff = (w * 4) * 512 + c * 32 + bswz;  // + jj*512

  f32x4 acc[8][4];
#pragma unroll
  for (int i = 0; i < 8; ++i)
#pragma unroll
    for (int j = 0; j < 4; ++j) acc[i][j] = 0.f;

  // A base per lane (f16 elems): row qt*16+c, colgroup quad
  const _Float16* gAl = gA + (size_t)c * DN + quad * 8;

  f16x8 a_cur[8], a_nxt[8];
#pragma unroll
  for (int qt = 0; qt < 8; ++qt) a_cur[qt] = *(const f16x8*)(gAl + (size_t)qt * 16 * DN);
#pragma unroll
  for (int j = 0; j < 4; ++j)
    DMA16(gB + (size_t)(w * 4 + j) * 1024, &Bb[0][(w * 4 + j) * 512]);

  for (int s = 0; s < 31; ++s) {
    const int cur = s & 1;
    const int sn = s + 1;
    // issue A(s+1) -> regs (8 ops)
#pragma unroll
    for (int qt = 0; qt < 8; ++qt)
      a_nxt[qt] = *(const f16x8*)(gAl + (size_t)qt * 16 * DN + sn * 32);
    // WAR fence: this wave's ds_reads on buf[cur^1] (iter s-1) drained before overwrite.
    asm volatile("s_waitcnt lgkmcnt(0)" ::: "memory");
    // issue B(s+1) -> LDS buf[cur^1] (wave-private slabs), contiguous stream (4 ops)
#pragma unroll
    for (int j = 0; j < 4; ++j)
      DMA16(gB + (size_t)sn * 65536 + (size_t)(w * 4 + j) * 1024, &Bb[cur ^ 1][(w * 4 + j) * 512]);
    // counted wait: allow A(s+1)+B(s+1)=12 in flight; forces A(s),B(s) landed
    asm volatile("s_waitcnt vmcnt(12)" ::: "memory");
    __builtin_amdgcn_sched_barrier(0);

    const _Float16* __restrict__ Bp = &Bb[cur][0];
#pragma unroll
    for (int jj = 0; jj < 4; ++jj) {
      const f16x8 bv = *(const f16x8*)(Bp + boff + jj * 512);
#pragma unroll
      for (int qt = 0; qt < 8; ++qt)
        acc[qt][jj] = __builtin_amdgcn_mfma_f32_16x16x32_f16(a_cur[qt], bv, acc[qt][jj], 0, 0, 0);
    }
#pragma unroll
    for (int qt = 0; qt < 8; ++qt) a_cur[qt] = a_nxt[qt];
  }
  // peeled final step (s=31, buffer 1): drain everything, compute, no issue
  asm volatile("s_waitcnt vmcnt(0)" ::: "memory");
  __builtin_amdgcn_sched_barrier(0);
  {
    const _Float16* __restrict__ Bp = &Bb[1][0];
#pragma unroll
    for (int jj = 0; jj < 4; ++jj) {
      const f16x8 bv = *(const f16x8*)(Bp + boff + jj * 512);
#pragma unroll
      for (int qt = 0; qt < 8; ++qt)
        acc[qt][jj] = __builtin_amdgcn_mfma_f32_16x16x32_f16(a_cur[qt], bv, acc[qt][jj], 0, 0, 0);
    }
  }

  // acc[qt][jj][r] = u  at row q = qt*16+quad*4+r , col l = w*64+jj*16+c
  float mx[8][4];
#pragma unroll
  for (int qt = 0; qt < 8; ++qt)
#pragma unroll
    for (int r = 0; r < 4; ++r) {
      float m = acc[qt][0][r];
#pragma unroll
      for (int jj = 1; jj < 4; ++jj) m = fmaxf(m, acc[qt][jj][r]);
      mx[qt][r] = m;
    }
#pragma unroll
  for (int off = 1; off < 16; off <<= 1)
#pragma unroll
    for (int qt = 0; qt < 8; ++qt)
#pragma unroll
      for (int r = 0; r < 4; ++r) mx[qt][r] = fmaxf(mx[qt][r], __shfl_xor(mx[qt][r], off, 64));
  if (c == 0)
#pragma unroll
    for (int qt = 0; qt < 8; ++qt)
#pragma unroll
      for (int r = 0; r < 4; ++r) maxbuf[w][qt * 16 + quad * 4 + r] = mx[qt][r];
  __syncthreads();
  if (tid < 128) {
    float m = maxbuf[0][tid];
#pragma unroll
    for (int ww = 1; ww < 16; ++ww) m = fmaxf(m, maxbuf[ww][tid]);
    Mbuf[tid] = m;
  }
  __syncthreads();

  const float KE = 0.045084220027780106f;  // log2(e)/32  (scores = u/sqrt(1024))
  float Mr[8][4], sl[8][4], nl[8][4];
#pragma unroll
  for (int qt = 0; qt < 8; ++qt)
#pragma unroll
    for (int r = 0; r < 4; ++r) {
      Mr[qt][r] = Mbuf[qt * 16 + quad * 4 + r];
      sl[qt][r] = 0.f;
      nl[qt][r] = 0.f;
    }
#pragma unroll
  for (int qt = 0; qt < 8; ++qt)
#pragma unroll
    for (int jj = 0; jj < 4; ++jj)
#pragma unroll
      for (int r = 0; r < 4; ++r) {
        const float u = acc[qt][jj][r];
        const float p = exp2f((u - Mr[qt][r]) * KE);
        acc[qt][jj][r] = p;
        sl[qt][r] += p;
        nl[qt][r] += p * u;
      }
#pragma unroll
  for (int off = 1; off < 16; off <<= 1)
#pragma unroll
    for (int qt = 0; qt < 8; ++qt)
#pragma unroll
      for (int r = 0; r < 4; ++r) {
        sl[qt][r] += __shfl_xor(sl[qt][r], off, 64);
        nl[qt][r] += __shfl_xor(nl[qt][r], off, 64);
      }
  if (c == 0)
#pragma unroll
    for (int qt = 0; qt < 8; ++qt)
#pragma unroll
      for (int r = 0; r < 4; ++r) {
        sumbuf[w][qt * 16 + quad * 4 + r] = sl[qt][r];
        numbuf[w][qt * 16 + quad * 4 + r] = nl[qt][r];
      }
  __syncthreads();
  if (tid < 128) {
    float S = 0.f, N = 0.f;
#pragma unroll
    for (int ww = 0; ww < 16; ++ww) {
      S += sumbuf[ww][tid];
      N += numbuf[ww][tid];
    }
    Rbuf[tid] = 1.0f / S;
    numv[(size_t)b * QN + q0 + tid] = N / S;  // = q . agg  (exact fp32 ratio)
  }
  __syncthreads();

  _Float16* Pb = P + ((size_t)b * QN + q0) * LN;
#pragma unroll
  for (int qt = 0; qt < 8; ++qt)
#pragma unroll
    for (int r = 0; r < 4; ++r) {
      const int row = qt * 16 + quad * 4 + r;
      const float rS = Rbuf[row];
      _Float16* prow = Pb + (size_t)row * LN + c;
#pragma unroll
      for (int jj = 0; jj < 4; ++jj) prow[w * 64 + jj * 16] = (_Float16)(acc[qt][jj][r] * rS);
    }
}

// ---------------- kernel 3: agg = P @ T (via TT2 images), ||agg||^2 per (b,q)
// same r10 structure: wave owns 128q x 64d; B = TT2 step images (rows=d, k=l)
__global__ __launch_bounds__(1024, 1) void k_agg(const _Float16* __restrict__ P,
                                                 const _Float16* __restrict__ TT2,
                                                 float* __restrict__ norm2) {
  __shared__ __align__(16) _Float16 Bb[2][32768];
  __shared__ float redbuf[16][128];
  int b, q0;
  decode_bq(blockIdx.x, b, q0);
  const int tid = threadIdx.x;
  const int w = tid >> 6, lane = tid & 63, c = lane & 15, quad = lane >> 4;

  const char* __restrict__ gB = (const char*)(TT2 + (size_t)b * 1048576) + lane * 16;
  const _Float16* __restrict__ gA = P + ((size_t)b * QN + q0) * LN;

  const int bswz = ((quad + ((c >> 1) & 3)) & 3) * 8;
  const int boff = (w * 4) * 512 + c * 32 + bswz;

  f32x4 acc[8][4];
#pragma unroll
  for (int i = 0; i < 8; ++i)
#pragma unroll
    for (int j = 0; j < 4; ++j) acc[i][j] = 0.f;

  const _Float16* gAl = gA + (size_t)c * LN + quad * 8;

  f16x8 a_cur[8], a_nxt[8];
#pragma unroll
  for (int qt = 0; qt < 8; ++qt) a_cur[qt] = *(const f16x8*)(gAl + (size_t)qt * 16 * LN);
#pragma unroll
  for (int j = 0; j < 4; ++j)
    DMA16(gB + (size_t)(w * 4 + j) * 1024, &Bb[0][(w * 4 + j) * 512]);

  for (int s = 0; s < 31; ++s) {
    const int cur = s & 1;
    const int sn = s + 1;
#pragma unroll
    for (int qt = 0; qt < 8; ++qt)
      a_nxt[qt] = *(const f16x8*)(gAl + (size_t)qt * 16 * LN + sn * 32);
    asm volatile("s_waitcnt lgkmcnt(0)" ::: "memory");
#pragma unroll
    for (int j = 0; j < 4; ++j)
      DMA16(gB + (size_t)sn * 65536 + (size_t)(w * 4 + j) * 1024, &Bb[cur ^ 1][(w * 4 + j) * 512]);
    asm volatile("s_waitcnt vmcnt(12)" ::: "memory");
    __builtin_amdgcn_sched_barrier(0);

    const _Float16* __restrict__ Bp = &Bb[cur][0];
#pragma unroll
    for (int jj = 0; jj < 4; ++jj) {
      const f16x8 bv = *(const f16x8*)(Bp + boff + jj * 512);
#pragma unroll
      for (int qt = 0; qt < 8; ++qt)
        acc[qt][jj] = __builtin_amdgcn_mfma_f32_16x16x32_f16(a_cur[qt], bv, acc[qt][jj], 0, 0, 0);
    }
#pragma unroll
    for (int qt = 0; qt < 8; ++qt) a_cur[qt] = a_nxt[qt];
  }
  asm volatile("s_waitcnt vmcnt(0)" ::: "memory");
  __builtin_amdgcn_sched_barrier(0);
  {
    const _Float16* __restrict__ Bp = &Bb[1][0];
#pragma unroll
    for (int jj = 0; jj < 4; ++jj) {
      const f16x8 bv = *(const f16x8*)(Bp + boff + jj * 512);
#pragma unroll
      for (int qt = 0; qt < 8; ++qt)
        acc[qt][jj] = __builtin_amdgcn_mfma_f32_16x16x32_f16(a_cur[qt], bv, acc[qt][jj], 0, 0, 0);
    }
  }

  // acc[qt][jj][r] at row q=qt*16+quad*4+r, col d=w*64+jj*16+c
  float ss[8][4];
#pragma unroll
  for (int qt = 0; qt < 8; ++qt)
#pragma unroll
    for (int r = 0; r < 4; ++r) {
      float s = 0.f;
#pragma unroll
      for (int jj = 0; jj < 4; ++jj) {
        const float v = acc[qt][jj][r];
        s += v * v;
      }
      ss[qt][r] = s;
    }
#pragma unroll
  for (int off = 1; off < 16; off <<= 1)
#pragma unroll
    for (int qt = 0; qt < 8; ++qt)
#pragma unroll
      for (int r = 0; r < 4; ++r) ss[qt][r] += __shfl_xor(ss[qt][r], off, 64);
  if (c == 0)
#pragma unroll
    for (int qt = 0; qt < 8; ++qt)
#pragma unroll
      for (int r = 0; r < 4; ++r) redbuf[w][qt * 16 + quad * 4 + r] = ss[qt][r];
  __syncthreads();
  if (tid < 128) {
    float s = 0.f;
#pragma unroll
    for (int ww = 0; ww < 16; ++ww) s += redbuf[ww][tid];
    norm2[(size_t)b * QN + q0 + tid] = s;
  }
}

// ---------------- kernel 4: logits[q][b] = num * invqn / max(||agg||, eps)
__global__ __launch_bounds__(256) void k_final(const float* __restrict__ numv,
                                               const float* __restrict__ norm2,
                                               const float* __restrict__ invqn,
                                               float* __restrict__ out) {
  const int idx = blockIdx.x * 256 + threadIdx.x;  // 0..32767
  const int q = idx >> 6, b = idx & 63;
  const float n = numv[(size_t)b * QN + q];
  const float d = sqrtf(norm2[(size_t)b * QN + q]);
  out[idx] = n * invqn[q] / fmaxf(d, 1e-12f);
}

extern "C" void kernel_launch(void* const* d_in, const int* in_sizes, int n_in,
                              void* d_out, int out_size, void* d_ws, size_t ws_size,
                              hipStream_t stream) {
  (void)in_sizes; (void)n_in; (void)out_size; (void)ws_size;
  const float* queries = (const float*)d_in[0];
  const float* tok = (const float*)d_in[1];
  float* out = (float*)d_out;
  char* ws = (char*)d_ws;

  // workspace layout (bytes)
  _Float16* T2 = (_Float16*)(ws + 0);           // 128 MB  staged images for k_scores
  _Float16* TT2 = (_Float16*)(ws + 134217728);  // 128 MB  staged images for k_agg
  _Float16* P = (_Float16*)(ws + 268435456);    // 64 MB   [b][q][l]
  _Float16* Qh = (_Float16*)(ws + 335544320);   // 1 MB    [q][d]
  float* invqn = (float*)(ws + 336592896);      // 2 KB
  float* numv = (float*)(ws + 336594944);       // 128 KB  [b][q]
  float* norm2 = (float*)(ws + 336726016);      // 128 KB  [b][q]

  hipLaunchKernelGGL(k_convert, dim3(16, 16, 64), dim3(256), 0, stream, tok, T2, TT2);
  hipLaunchKernelGGL(k_queries, dim3(512), dim3(256), 0, stream, queries, Qh, invqn);
  hipLaunchKernelGGL(k_scores, dim3(256), dim3(1024), 0, stream, Qh, T2, P, numv);
  hipLaunchKernelGGL(k_agg, dim3(256), dim3(1024), 0, stream, P, TT2, norm2);
  hipLaunchKernelGGL(k_final, dim3(128), dim3(256), 0, stream, numv, norm2, invqn, out);
}